// Round 1
// baseline (357.578 us; speedup 1.0000x reference)
//
#include <hip/hip_runtime.h>

#define N_NODES 100000
#define N_EDGES 1600000
#define D_FEAT  64

// out[v][d] = bias[d]  (full re-init every call: harness poisons d_out once
// and never re-poisons between timed replays)
__global__ void init_out_kernel(const float* __restrict__ bias,
                                float* __restrict__ out) {
    int i = blockIdx.x * blockDim.x + threadIdx.x;
    if (i < N_NODES * D_FEAT) {
        out[i] = bias[i & (D_FEAT - 1)];
    }
}

// One 64-lane wave per edge; lane d handles feature dim d.
// atomicAdd(&out[dst*64 + d], w * feat[src*64 + d])
__global__ void edge_scatter_kernel(const float* __restrict__ feat,
                                    const float* __restrict__ weight,
                                    const int* __restrict__ src,
                                    const int* __restrict__ dst,
                                    float* __restrict__ out) {
    // 256 threads/block = 4 edges/block
    int e = blockIdx.x * 4 + (threadIdx.x >> 6);
    int lane = threadIdx.x & 63;
    if (e < N_EDGES) {
        int s = src[e];
        int v = dst[e];
        float w = weight[e];
        float f = feat[s * D_FEAT + lane];
        atomicAdd(&out[v * D_FEAT + lane], w * f);
    }
}

extern "C" void kernel_launch(void* const* d_in, const int* in_sizes, int n_in,
                              void* d_out, int out_size, void* d_ws, size_t ws_size,
                              hipStream_t stream) {
    const float* feat   = (const float*)d_in[0];
    const float* weight = (const float*)d_in[1];
    const float* bias   = (const float*)d_in[2];
    const int*   src    = (const int*)d_in[3];
    const int*   dst    = (const int*)d_in[4];
    float* out = (float*)d_out;

    {
        int total = N_NODES * D_FEAT;
        int threads = 256;
        int blocks = (total + threads - 1) / threads;
        init_out_kernel<<<blocks, threads, 0, stream>>>(bias, out);
    }
    {
        int threads = 256;                       // 4 edges per block
        int blocks = (N_EDGES + 3) / 4;
        edge_scatter_kernel<<<blocks, threads, 0, stream>>>(feat, weight, src, dst, out);
    }
}